// Round 1
// baseline (163.779 us; speedup 1.0000x reference)
//
#include <hip/hip_runtime.h>

constexpr int BLOCK = 256;
constexpr int SPT = 2;                    // samples per thread (consecutive)
constexpr int SPB = BLOCK * SPT;          // 512 samples per block
constexpr int HALO_LO = 10;               // l_max(7) + m_max(3)
constexpr int HALO_HI = 3;                // +m_max for the c (leading) term
constexpr int SIG = SPB + HALO_LO + HALO_HI;   // 525 staged signal entries

// y[n] = sum_l x[n-l] * ( P0_l(|x[n-l]|) + sum_{m=1..3} Pb_{l,m}(|x[n-l-m]|)
//                                        + sum_{m=1..3} Pc_{l,m}(|x[n-l+m]|) )
// where P0 folds a[:,l] + b[:,l,0] + c[:,l,0] (identical radius at m=0).
// All indices clipped to [0, N-1] — handled once at LDS staging time.

__global__ __launch_bounds__(BLOCK) void gmp_kernel(
    const float* __restrict__ x,
    const float* __restrict__ a_re, const float* __restrict__ a_im,
    const float* __restrict__ b_re, const float* __restrict__ b_im,
    const float* __restrict__ c_re, const float* __restrict__ c_im,
    float* __restrict__ out, int N)
{
    __shared__ float sxr[SIG], sxi[SIG], sab[SIG];
    // scoef[l][slot][k]: slot 0 = folded m=0; slots 1..3 = b m=1..3; 4..6 = c m=1..3
    __shared__ __align__(16) float2 scoef[8][7][8];

    const int t = threadIdx.x;
    const int n0 = blockIdx.x * SPB;

    // ---- stage coefficients (448 complex entries) ----
    for (int idx = t; idx < 448; idx += BLOCK) {
        int l = idx / 56;
        int rem = idx - l * 56;
        int s = rem >> 3;
        int k = rem & 7;
        int akl = k * 8 + l;          // a[k][l] flat; b/c[k][l][m] = akl*4 + m
        float re, im;
        if (s == 0) {
            re = a_re[akl] + b_re[akl * 4] + c_re[akl * 4];
            im = a_im[akl] + b_im[akl * 4] + c_im[akl * 4];
        } else if (s <= 3) {
            re = b_re[akl * 4 + s];
            im = b_im[akl * 4 + s];
        } else {
            re = c_re[akl * 4 + (s - 3)];
            im = c_im[akl * 4 + (s - 3)];
        }
        scoef[l][s][k] = make_float2(re, im);
    }

    // ---- stage signal + envelope with clipped halo ----
    const float2* x2 = (const float2*)x;
    for (int j = t; j < SIG; j += BLOCK) {
        int g = n0 - HALO_LO + j;
        g = max(0, min(N - 1, g));
        float2 v = x2[g];
        sxr[j] = v.x;
        sxi[j] = v.y;
        sab[j] = sqrtf(fmaf(v.x, v.x, v.y * v.y));
    }
    __syncthreads();

    // ---- register-cache this thread's window ----
    // samples p0 = 2t, p1 = 2t+1 (local); smem center j_p = p + HALO_LO
    const int jb = 2 * t;
    float rv[15];                 // rv[i] = |x| at smem index jb + i
    #pragma unroll
    for (int i = 0; i < 15; ++i) rv[i] = sab[jb + i];
    float xr[9], xi[9];           // x at smem index jb + 3 + i
    #pragma unroll
    for (int i = 0; i < 9; ++i) { xr[i] = sxr[jb + 3 + i]; xi[i] = sxi[jb + 3 + i]; }

    float y00 = 0.f, y01 = 0.f, y10 = 0.f, y11 = 0.f;

    #pragma unroll
    for (int l = 0; l < 8; ++l) {
        float S0r = 0.f, S0i = 0.f, S1r = 0.f, S1i = 0.f;
        #pragma unroll
        for (int s = 0; s < 7; ++s) {
            const float4* cp = (const float4*)(&scoef[l][s][0]);
            float4 c01 = cp[0], c23 = cp[1], c45 = cp[2], c67 = cp[3];
            const int d = (s == 0) ? 0 : ((s <= 3) ? -s : (s - 3));
            #pragma unroll
            for (int q = 0; q < 2; ++q) {
                float r = rv[10 + q - l + d];
                float ar = c67.z, ai = c67.w;                 // k = 7
                ar = fmaf(ar, r, c67.x); ai = fmaf(ai, r, c67.y);  // k = 6
                ar = fmaf(ar, r, c45.z); ai = fmaf(ai, r, c45.w);  // k = 5
                ar = fmaf(ar, r, c45.x); ai = fmaf(ai, r, c45.y);  // k = 4
                ar = fmaf(ar, r, c23.z); ai = fmaf(ai, r, c23.w);  // k = 3
                ar = fmaf(ar, r, c23.x); ai = fmaf(ai, r, c23.y);  // k = 2
                ar = fmaf(ar, r, c01.z); ai = fmaf(ai, r, c01.w);  // k = 1
                ar = fmaf(ar, r, c01.x); ai = fmaf(ai, r, c01.y);  // k = 0
                if (q == 0) { S0r += ar; S0i += ai; }
                else        { S1r += ar; S1i += ai; }
            }
        }
        {
            float xre = xr[7 - l], xim_ = xi[7 - l];
            y00 = fmaf(xre, S0r, fmaf(-xim_, S0i, y00));
            y01 = fmaf(xre, S0i, fmaf( xim_, S0r, y01));
        }
        {
            float xre = xr[8 - l], xim_ = xi[8 - l];
            y10 = fmaf(xre, S1r, fmaf(-xim_, S1i, y10));
            y11 = fmaf(xre, S1i, fmaf( xim_, S1r, y11));
        }
    }

    const int nb = n0 + 2 * t;
    if (nb + 1 < N) {
        float4* o4 = (float4*)(out + 2 * nb);
        *o4 = make_float4(y00, y01, y10, y11);
    } else if (nb < N) {
        out[2 * nb]     = y00;
        out[2 * nb + 1] = y01;
    }
}

extern "C" void kernel_launch(void* const* d_in, const int* in_sizes, int n_in,
                              void* d_out, int out_size, void* d_ws, size_t ws_size,
                              hipStream_t stream) {
    const float* x    = (const float*)d_in[0];
    const float* a_re = (const float*)d_in[1];
    const float* a_im = (const float*)d_in[2];
    const float* b_re = (const float*)d_in[3];
    const float* b_im = (const float*)d_in[4];
    const float* c_re = (const float*)d_in[5];
    const float* c_im = (const float*)d_in[6];
    float* out = (float*)d_out;

    int N = in_sizes[0] / 2;
    int grid = (N + SPB - 1) / SPB;
    gmp_kernel<<<grid, BLOCK, 0, stream>>>(x, a_re, a_im, b_re, b_im,
                                           c_re, c_im, out, N);
}

// Round 2
// 154.960 us; speedup vs baseline: 1.0569x; 1.0569x over previous
//
#include <hip/hip_runtime.h>

constexpr int BLOCK = 256;
constexpr int SPT = 2;                    // samples per thread (consecutive)
constexpr int SPB = BLOCK * SPT;          // 512 samples per block
constexpr int HALO_LO = 10;               // l_max(7) + m_max(3)
constexpr int HALO_HI = 3;                // +m_max for the c (leading) term
constexpr int SIG = SPB + HALO_LO + HALO_HI;   // 525 staged signal entries

// y[n] = sum_l x[n-l] * ( P0_l(|x[n-l]|) + sum_{m=1..3} Pb_{l,m}(|x[n-l-m]|)
//                                        + sum_{m=1..3} Pc_{l,m}(|x[n-l+m]|) )
// P0 folds a[:,l] + b[:,l,0] + c[:,l,0] (identical radius at m=0).
// Coefficients are wave-uniform -> read straight from global with
// compile-time-constant indices so the compiler emits s_load (SGPR,
// scalar cache). No LDS, no VGPR cost for coefficients => no spills.

__global__ __launch_bounds__(BLOCK) void gmp_kernel(
    const float* __restrict__ x,
    const float* __restrict__ a_re, const float* __restrict__ a_im,
    const float* __restrict__ b_re, const float* __restrict__ b_im,
    const float* __restrict__ c_re, const float* __restrict__ c_im,
    float* __restrict__ out, int N)
{
    __shared__ float sxr[SIG], sxi[SIG], sab[SIG];

    const int t = threadIdx.x;
    const int n0 = blockIdx.x * SPB;

    // ---- stage signal + envelope with clipped halo ----
    const float2* x2 = (const float2*)x;
    for (int j = t; j < SIG; j += BLOCK) {
        int g = n0 - HALO_LO + j;
        g = max(0, min(N - 1, g));
        float2 v = x2[g];
        sxr[j] = v.x;
        sxi[j] = v.y;
        sab[j] = sqrtf(fmaf(v.x, v.x, v.y * v.y));
    }
    __syncthreads();

    // ---- register-cache this thread's window (static indices only) ----
    const int jb = 2 * t;
    float rv[15];                 // rv[i] = |x| at smem index jb + i
    #pragma unroll
    for (int i = 0; i < 15; ++i) rv[i] = sab[jb + i];
    float xr[9], xi[9];           // x at smem index jb + 3 + i
    #pragma unroll
    for (int i = 0; i < 9; ++i) { xr[i] = sxr[jb + 3 + i]; xi[i] = sxi[jb + 3 + i]; }

    float y00 = 0.f, y01 = 0.f, y10 = 0.f, y11 = 0.f;

    #pragma unroll
    for (int l = 0; l < 8; ++l) {
        float S0r = 0.f, S0i = 0.f, S1r = 0.f, S1i = 0.f;
        #pragma unroll
        for (int s = 0; s < 7; ++s) {
            // coefficient fetch: uniform scalar loads, constant indices
            float cr[8], ci[8];
            #pragma unroll
            for (int k = 0; k < 8; ++k) {
                const int akl = k * 8 + l;       // a[k][l]; b/c[k][l][m] = akl*4+m
                if (s == 0) {
                    cr[k] = a_re[akl] + b_re[akl * 4] + c_re[akl * 4];
                    ci[k] = a_im[akl] + b_im[akl * 4] + c_im[akl * 4];
                } else if (s <= 3) {
                    cr[k] = b_re[akl * 4 + s];
                    ci[k] = b_im[akl * 4 + s];
                } else {
                    cr[k] = c_re[akl * 4 + (s - 3)];
                    ci[k] = c_im[akl * 4 + (s - 3)];
                }
            }
            const int d = (s == 0) ? 0 : ((s <= 3) ? -s : (s - 3));
            #pragma unroll
            for (int q = 0; q < 2; ++q) {
                float r = rv[10 + q - l + d];
                float ar = cr[7], ai = ci[7];
                #pragma unroll
                for (int k = 6; k >= 0; --k) {
                    ar = fmaf(ar, r, cr[k]);
                    ai = fmaf(ai, r, ci[k]);
                }
                if (q == 0) { S0r += ar; S0i += ai; }
                else        { S1r += ar; S1i += ai; }
            }
        }
        {
            float xre = xr[7 - l], xim_ = xi[7 - l];
            y00 = fmaf(xre, S0r, fmaf(-xim_, S0i, y00));
            y01 = fmaf(xre, S0i, fmaf( xim_, S0r, y01));
        }
        {
            float xre = xr[8 - l], xim_ = xi[8 - l];
            y10 = fmaf(xre, S1r, fmaf(-xim_, S1i, y10));
            y11 = fmaf(xre, S1i, fmaf( xim_, S1r, y11));
        }
    }

    const int nb = n0 + 2 * t;
    if (nb + 1 < N) {
        float4* o4 = (float4*)(out + 2 * nb);
        *o4 = make_float4(y00, y01, y10, y11);
    } else if (nb < N) {
        out[2 * nb]     = y00;
        out[2 * nb + 1] = y01;
    }
}

extern "C" void kernel_launch(void* const* d_in, const int* in_sizes, int n_in,
                              void* d_out, int out_size, void* d_ws, size_t ws_size,
                              hipStream_t stream) {
    const float* x    = (const float*)d_in[0];
    const float* a_re = (const float*)d_in[1];
    const float* a_im = (const float*)d_in[2];
    const float* b_re = (const float*)d_in[3];
    const float* b_im = (const float*)d_in[4];
    const float* c_re = (const float*)d_in[5];
    const float* c_im = (const float*)d_in[6];
    float* out = (float*)d_out;

    int N = in_sizes[0] / 2;
    int grid = (N + SPB - 1) / SPB;
    gmp_kernel<<<grid, BLOCK, 0, stream>>>(x, a_re, a_im, b_re, b_im,
                                           c_re, c_im, out, N);
}

// Round 3
// 78.984 us; speedup vs baseline: 2.0736x; 1.9619x over previous
//
#include <hip/hip_runtime.h>
#include <type_traits>

constexpr int BLOCK = 256;
constexpr int HALO_LO = 10;               // l_max(7) + m_max(3)
constexpr int HALO_HI = 3;                // +m_max for the c (leading) term
constexpr int SPB = BLOCK;                // 1 sample per thread
constexpr int SIG = SPB + HALO_LO + HALO_HI;   // 269 staged entries

// ---------------- compile-time unroll helper ----------------
template<int I, int N, typename F>
__device__ __forceinline__ void unroll_for(F&& f) {
    if constexpr (I < N) {
        f(std::integral_constant<int, I>{});
        unroll_for<I + 1, N>(static_cast<F&&>(f));
    }
}

// ---------------- kernel 1: fold coefficients ----------------
// W[l][s][k] complex, packed ws[((l*7+s)*8+k)*2 + {0:re,1:im}].
// slot 0 = a[:,l] + b[:,l,0] + c[:,l,0]; slots 1..3 = b m=1..3; 4..6 = c m=1..3.
__global__ void prefold_kernel(
    const float* __restrict__ a_re, const float* __restrict__ a_im,
    const float* __restrict__ b_re, const float* __restrict__ b_im,
    const float* __restrict__ c_re, const float* __restrict__ c_im,
    float* __restrict__ w)
{
    int idx = blockIdx.x * blockDim.x + threadIdx.x;
    if (idx >= 448) return;
    int l = idx / 56;
    int rem = idx - l * 56;
    int s = rem >> 3;
    int k = rem & 7;
    int akl = k * 8 + l;                  // a[k][l]; b/c[k][l][m] = akl*4 + m
    float re, im;
    if (s == 0) {
        re = a_re[akl] + b_re[akl * 4] + c_re[akl * 4];
        im = a_im[akl] + b_im[akl * 4] + c_im[akl * 4];
    } else if (s <= 3) {
        re = b_re[akl * 4 + s];
        im = b_im[akl * 4 + s];
    } else {
        re = c_re[akl * 4 + (s - 3)];
        im = c_im[akl * 4 + (s - 3)];
    }
    w[idx * 2]     = re;
    w[idx * 2 + 1] = im;
}

// ---------------- kernel 2: main GMP ----------------
// y[n] = sum_l x[n-l] * sum_s P_{l,s}(r[n-l+d(s)]),  d: 0,-1,-2,-3,+1,+2,+3
__global__ __launch_bounds__(BLOCK) void gmp_kernel(
    const float* __restrict__ x,
    const float* __restrict__ w,         // folded coefficients (448 complex)
    float* __restrict__ out, int N)
{
    __shared__ float sxr[SIG], sxi[SIG], sab[SIG];

    const int t = threadIdx.x;
    const int n0 = blockIdx.x * SPB;

    // stage signal + envelope with clipped halo
    const float2* x2 = (const float2*)x;
    for (int j = t; j < SIG; j += BLOCK) {
        int g = n0 - HALO_LO + j;
        g = max(0, min(N - 1, g));
        float2 v = x2[g];
        sxr[j] = v.x;
        sxi[j] = v.y;
        sab[j] = sqrtf(fmaf(v.x, v.x, v.y * v.y));
    }
    __syncthreads();

    // register-cache the window (all indices compile-time offsets from t)
    float rv[14];                  // radius at offset o = i - 10 from n
    unroll_for<0, 14>([&](auto I) { rv[I.value] = sab[t + I.value]; });
    float xr[8], xi[8];            // x at lag l: index 7 - l
    unroll_for<0, 8>([&](auto I) {
        xr[I.value] = sxr[t + 3 + I.value];
        xi[I.value] = sxi[t + 3 + I.value];
    });

    float yr = 0.f, yi = 0.f;

    unroll_for<0, 8>([&](auto Lc) {
        constexpr int L = Lc.value;
        float Sr = 0.f, Si = 0.f;
        unroll_for<0, 7>([&](auto Sc) {
            constexpr int S = Sc.value;
            constexpr int d = (S == 0) ? 0 : ((S <= 3) ? -S : (S - 3));
            constexpr int base = (L * 7 + S) * 16;   // 16 floats per slot
            const float r = rv[10 - L + d];
            float ar = w[base + 14], ai = w[base + 15];     // k = 7
            unroll_for<0, 7>([&](auto Kc) {
                constexpr int k = 6 - Kc.value;
                ar = fmaf(ar, r, w[base + 2 * k]);
                ai = fmaf(ai, r, w[base + 2 * k + 1]);
            });
            Sr += ar;
            Si += ai;
        });
        const float xre = xr[7 - L], xim = xi[7 - L];
        yr = fmaf(xre, Sr, fmaf(-xim, Si, yr));
        yi = fmaf(xre, Si, fmaf( xim, Sr, yi));
    });

    const int n = n0 + t;
    if (n < N) {
        float2* o2 = (float2*)(out + 2 * n);
        *o2 = make_float2(yr, yi);
    }
}

extern "C" void kernel_launch(void* const* d_in, const int* in_sizes, int n_in,
                              void* d_out, int out_size, void* d_ws, size_t ws_size,
                              hipStream_t stream) {
    const float* x    = (const float*)d_in[0];
    const float* a_re = (const float*)d_in[1];
    const float* a_im = (const float*)d_in[2];
    const float* b_re = (const float*)d_in[3];
    const float* b_im = (const float*)d_in[4];
    const float* c_re = (const float*)d_in[5];
    const float* c_im = (const float*)d_in[6];
    float* out = (float*)d_out;
    float* w   = (float*)d_ws;            // 448 * 2 * 4 = 3584 bytes

    int N = in_sizes[0] / 2;
    prefold_kernel<<<2, 256, 0, stream>>>(a_re, a_im, b_re, b_im, c_re, c_im, w);
    int grid = (N + SPB - 1) / SPB;
    gmp_kernel<<<grid, BLOCK, 0, stream>>>(x, w, out, N);
}

// Round 4
// 78.755 us; speedup vs baseline: 2.0796x; 1.0029x over previous
//
#include <hip/hip_runtime.h>
#include <type_traits>

typedef float v2f __attribute__((ext_vector_type(2)));

constexpr int BLOCK = 256;
constexpr int HALO_LO = 10;               // l_max(7) + m_max(3)
constexpr int HALO_HI = 3;                // +m_max for the c (leading) term
constexpr int SPB = BLOCK;                // 1 sample per thread
constexpr int SIG = SPB + HALO_LO + HALO_HI;

// ---------------- compile-time unroll helper ----------------
template<int I, int N, typename F>
__device__ __forceinline__ void unroll_for(F&& f) {
    if constexpr (I < N) {
        f(std::integral_constant<int, I>{});
        unroll_for<I + 1, N>(static_cast<F&&>(f));
    }
}

// ---------------- kernel 1: fold coefficients ----------------
// W[l][s][k] complex, packed as (re,im) pairs: w2[(l*7+s)*8 + k].
// slot 0 = a[:,l] + b[:,l,0] + c[:,l,0]; slots 1..3 = b m=1..3; 4..6 = c m=1..3.
__global__ void prefold_kernel(
    const float* __restrict__ a_re, const float* __restrict__ a_im,
    const float* __restrict__ b_re, const float* __restrict__ b_im,
    const float* __restrict__ c_re, const float* __restrict__ c_im,
    float* __restrict__ w)
{
    int idx = threadIdx.x;
    if (idx >= 448) return;
    int l = idx / 56;
    int rem = idx - l * 56;
    int s = rem >> 3;
    int k = rem & 7;
    int akl = k * 8 + l;                  // a[k][l]; b/c[k][l][m] = akl*4 + m
    float re, im;
    if (s == 0) {
        re = a_re[akl] + b_re[akl * 4] + c_re[akl * 4];
        im = a_im[akl] + b_im[akl * 4] + c_im[akl * 4];
    } else if (s <= 3) {
        re = b_re[akl * 4 + s];
        im = b_im[akl * 4 + s];
    } else {
        re = c_re[akl * 4 + (s - 3)];
        im = c_im[akl * 4 + (s - 3)];
    }
    w[idx * 2]     = re;
    w[idx * 2 + 1] = im;
}

// ---------------- kernel 2: main GMP ----------------
// y[n] = sum_l x[n-l] * sum_s P_{l,s}(r[n-l+d(s)]),  d: 0,-1,-2,-3,+1,+2,+3
// Horner in packed (re,im) pairs -> v_pk_fma_f32.
__global__ __launch_bounds__(BLOCK) void gmp_kernel(
    const float* __restrict__ x,
    const v2f* __restrict__ w2,          // folded coefficients (448 pairs)
    float* __restrict__ out, int N)
{
    __shared__ float sxr[SIG], sxi[SIG], sab[SIG];

    const int t = threadIdx.x;
    const int n0 = blockIdx.x * SPB;

    // stage signal + envelope with clipped halo
    const float2* x2 = (const float2*)x;
    for (int j = t; j < SIG; j += BLOCK) {
        int g = n0 - HALO_LO + j;
        g = max(0, min(N - 1, g));
        float2 v = x2[g];
        sxr[j] = v.x;
        sxi[j] = v.y;
        sab[j] = sqrtf(fmaf(v.x, v.x, v.y * v.y));
    }
    __syncthreads();

    // register-cache the window (all indices compile-time offsets from t)
    float rv[14];                  // radius at global offset (i - 10) from n
    unroll_for<0, 14>([&](auto I) { rv[I.value] = sab[t + I.value]; });
    float xr[8], xi[8];            // x at lag l: index 7 - l
    unroll_for<0, 8>([&](auto I) {
        xr[I.value] = sxr[t + 3 + I.value];
        xi[I.value] = sxi[t + 3 + I.value];
    });

    float yr = 0.f, yi = 0.f;

    unroll_for<0, 8>([&](auto Lc) {
        constexpr int L = Lc.value;
        v2f S = {0.f, 0.f};
        unroll_for<0, 7>([&](auto Sc) {
            constexpr int Sl = Sc.value;
            constexpr int d = (Sl == 0) ? 0 : ((Sl <= 3) ? -Sl : (Sl - 3));
            constexpr int base = (L * 7 + Sl) * 8;   // 8 pairs per slot
            const float r = rv[10 - L + d];
            const v2f rr = {r, r};
            v2f acc = w2[base + 7];                  // k = 7
            unroll_for<0, 7>([&](auto Kc) {
                constexpr int k = 6 - Kc.value;
                acc = __builtin_elementwise_fma(acc, rr, w2[base + k]);
            });
            S += acc;                                // v_pk_add_f32
        });
        const float xre = xr[7 - L], xim = xi[7 - L];
        yr = fmaf(xre, S.x, fmaf(-xim, S.y, yr));
        yi = fmaf(xre, S.y, fmaf( xim, S.x, yi));
    });

    const int n = n0 + t;
    if (n < N) {
        float2* o2 = (float2*)(out + 2 * n);
        *o2 = make_float2(yr, yi);
    }
}

extern "C" void kernel_launch(void* const* d_in, const int* in_sizes, int n_in,
                              void* d_out, int out_size, void* d_ws, size_t ws_size,
                              hipStream_t stream) {
    const float* x    = (const float*)d_in[0];
    const float* a_re = (const float*)d_in[1];
    const float* a_im = (const float*)d_in[2];
    const float* b_re = (const float*)d_in[3];
    const float* b_im = (const float*)d_in[4];
    const float* c_re = (const float*)d_in[5];
    const float* c_im = (const float*)d_in[6];
    float* out = (float*)d_out;
    float* w   = (float*)d_ws;            // 448 * 2 * 4 = 3584 bytes used

    int N = in_sizes[0] / 2;
    prefold_kernel<<<1, 448, 0, stream>>>(a_re, a_im, b_re, b_im, c_re, c_im, w);
    int grid = (N + SPB - 1) / SPB;
    gmp_kernel<<<grid, BLOCK, 0, stream>>>(x, (const v2f*)w, out, N);
}